// Round 10
// baseline (1089.813 us; speedup 1.0000x reference)
//
#include <hip/hip_runtime.h>
#include <hip/hip_bf16.h>
#include <math.h>

using bf16 = __hip_bfloat16;
typedef __bf16 bf16x8 __attribute__((ext_vector_type(8)));
typedef float  f32x4  __attribute__((ext_vector_type(4)));

#define BK 64   // K-tile; row stride 128B, XOR-swizzled chunks

// ---------------------------------------------------------------------------
// Catmull-Rom spline reconstruction: cp[n_ctrl] -> w[n] (bf16), 8 outputs/thread.
// ---------------------------------------------------------------------------
__global__ void spline_recon8_kernel(const float* __restrict__ cp,
                                     bf16* __restrict__ w,
                                     int n8, int n_ctrl, double step) {
    int k8 = blockIdx.x * blockDim.x + threadIdx.x;
    if (k8 >= n8) return;
    long long kbase = (long long)k8 * 8;
    bf16x8 o;
#pragma unroll
    for (int u = 0; u < 8; ++u) {
        double t = (double)(kbase + u) * step;
        int i = (int)t;
        if (i > n_ctrl - 2) i = n_ctrl - 2;
        float f = (float)(t - (double)i);
        float p0 = cp[i > 0 ? i - 1 : 0];
        float p1 = cp[i];
        float p2 = cp[i + 1];
        float p3 = cp[(i + 2) <= (n_ctrl - 1) ? (i + 2) : (n_ctrl - 1)];
        float f2 = f * f;
        float f3 = f2 * f;
        float v = 0.5f * (2.0f * p1
                          + (p2 - p0) * f
                          + (2.0f * p0 - 5.0f * p1 + 4.0f * p2 - p3) * f2
                          + (3.0f * p1 - p0 - 3.0f * p2 + p3) * f3);
        o[u] = (__bf16)v;
    }
    *reinterpret_cast<bf16x8*>(w + kbase) = o;
}

// fp32 -> bf16 cast, 8 elements/thread
__global__ void cvt_f32_bf16_8_kernel(const float4* __restrict__ x,
                                      bf16* __restrict__ y, int n8) {
    int k = blockIdx.x * blockDim.x + threadIdx.x;
    if (k >= n8) return;
    float4 a = x[2 * k];
    float4 b = x[2 * k + 1];
    bf16x8 o;
    o[0] = (__bf16)a.x; o[1] = (__bf16)a.y; o[2] = (__bf16)a.z; o[3] = (__bf16)a.w;
    o[4] = (__bf16)b.x; o[5] = (__bf16)b.y; o[6] = (__bf16)b.z; o[7] = (__bf16)b.w;
    *reinterpret_cast<bf16x8*>(y + (long long)k * 8) = o;
}

__device__ __forceinline__ void async_load16(const bf16* g, bf16* l) {
    __builtin_amdgcn_global_load_lds(
        (const __attribute__((address_space(1))) void*)g,
        (__attribute__((address_space(3))) void*)l,
        16, 0, 0);
}

// raw barrier with compiler memory fences (prevents LDS op reordering across it)
__device__ __forceinline__ void raw_barrier() {
    asm volatile("" ::: "memory");
    __builtin_amdgcn_s_barrier();
    asm volatile("" ::: "memory");
}

#define WAIT_VM8()  asm volatile("s_waitcnt vmcnt(8)" ::: "memory")
#define WAIT_VM0()  asm volatile("s_waitcnt vmcnt(0)" ::: "memory")

// ---------------------------------------------------------------------------
// Fused gate+up GEMM, R15 ("fused2"): 256(M)x128(N) tile, BOTH-per-wave.
// R5 geometry (128x128, gate/up wave split) stages 48KB per 4.19 MFLOP
// (87 FLOP/B) and needs an LDS Epi exchange. New: 8 waves in 4x2; each wave
// computes gate AND up for its 64x64 sub-tile (acc_g[4][4]+acc_u[4][4] =
// 128 VGPR). Staging A 32K + Bg 16K + Bu 16K = 64KB per 8.39 MFLOP
// (128 FLOP/B, 1.47x); total staged 6.3 -> 4.2 GB. Epilogue is pure
// in-register silu(g)*u — no Epi LDS round-trip, no extra barrier, all
// waves store. Counted-vmcnt dbuf skeleton (validated in down6/down8):
// 2x64KB LDS, 8 loads/STAGE -> vmcnt(8). 1 blk/CU; natural x-major grid
// (64x32) gives each XCD 8 bcols x 4 brows -> 384KB/XCD/iter shared set
// (same partitioning as R5's implicit window — FETCH should hold).
// Per-element math identical to R5 (same fragment order, same silu).
// ---------------------------------------------------------------------------
__global__ __launch_bounds__(512, 2) void fused_gate_up2_kernel(
    const bf16* __restrict__ A,    // X  [M, K]
    const bf16* __restrict__ Bg,   // Wg [N, K]
    const bf16* __restrict__ Bu,   // Wu [N, K]
    bf16* __restrict__ C,          // inter [M, N]
    int M, int N, int K) {
    __shared__ __align__(16) bf16 smem[2 * 2 * 256 * BK];  // 128 KB dbuf
    bf16* As0  = smem;                 // 256x64 = 16384 elems (32 KB)
    bf16* Bgs0 = smem + 16384;         // 128x64 =  8192 elems (16 KB)
    bf16* Bus0 = smem + 24576;
    bf16* As1  = smem + 32768;
    bf16* Bgs1 = smem + 49152;
    bf16* Bus1 = smem + 57344;

    const int tid  = threadIdx.x;
    const int lane = tid & 63;
    const int wave = tid >> 6;            // 0..7, 4(M) x 2(N)
    const int wm   = (wave >> 1) * 64;    // 0,64,128,192
    const int wn   = (wave & 1) * 64;     // 0,64

    const long long brow = (long long)blockIdx.y * 256;
    const long long bcol = (long long)blockIdx.x * 128;

    const int srow = tid >> 3;                       // 0..63
    const int skb  = ((tid & 7) ^ (srow & 7)) * 8;   // swizzled global col (elems)
    const bf16* ga0 = A  + (brow + srow) * (long long)K + skb;
    const bf16* ga1 = A  + (brow + srow + 64) * (long long)K + skb;
    const bf16* ga2 = A  + (brow + srow + 128) * (long long)K + skb;
    const bf16* ga3 = A  + (brow + srow + 192) * (long long)K + skb;
    const bf16* gg0 = Bg + (bcol + srow) * (long long)K + skb;
    const bf16* gg1 = Bg + (bcol + srow + 64) * (long long)K + skb;
    const bf16* gu0 = Bu + (bcol + srow) * (long long)K + skb;
    const bf16* gu1 = Bu + (bcol + srow + 64) * (long long)K + skb;

    const int fm = wm + (lane & 15);
    const int fn = wn + (lane & 15);
    const int qk = lane >> 4;              // 0..3 (k-quad)

    f32x4 acc_g[4][4] = {};
    f32x4 acc_u[4][4] = {};

    // stage tile t: 8 global_load_lds per thread (4 A + 2 Bg + 2 Bu)
#define STAGE_F(dA, dG, dU, t)                                             \
    do {                                                                   \
        long long off = (long long)(t) * BK;                               \
        async_load16(ga0 + off, (dA) + tid * 8);                           \
        async_load16(ga1 + off, (dA) + 4096 + tid * 8);                    \
        async_load16(ga2 + off, (dA) + 8192 + tid * 8);                    \
        async_load16(ga3 + off, (dA) + 12288 + tid * 8);                   \
        async_load16(gg0 + off, (dG) + tid * 8);                           \
        async_load16(gg1 + off, (dG) + 4096 + tid * 8);                    \
        async_load16(gu0 + off, (dU) + tid * 8);                           \
        async_load16(gu1 + off, (dU) + 4096 + tid * 8);                    \
    } while (0)

#define COMPUTE_F(sA, sG, sU)                                              \
    do {                                                                   \
        _Pragma("unroll")                                                  \
        for (int h = 0; h < 2; ++h) {                                      \
            bf16x8 afr[4], bgr[4], bur[4];                                 \
            const int hc = (h << 2) | qk;                                  \
            const int ccA = (hc ^ (fm & 7)) * 8;                           \
            const int ccB = (hc ^ (fn & 7)) * 8;                           \
            _Pragma("unroll")                                              \
            for (int i = 0; i < 4; ++i)                                    \
                afr[i] = *reinterpret_cast<const bf16x8*>(                 \
                    &(sA)[(fm + i * 16) * BK + ccA]);                      \
            _Pragma("unroll")                                              \
            for (int j = 0; j < 4; ++j) {                                  \
                bgr[j] = *reinterpret_cast<const bf16x8*>(                 \
                    &(sG)[(fn + j * 16) * BK + ccB]);                      \
                bur[j] = *reinterpret_cast<const bf16x8*>(                 \
                    &(sU)[(fn + j * 16) * BK + ccB]);                      \
            }                                                              \
            _Pragma("unroll")                                              \
            for (int i = 0; i < 4; ++i)                                    \
                _Pragma("unroll")                                          \
                for (int j = 0; j < 4; ++j) {                              \
                    acc_g[i][j] = __builtin_amdgcn_mfma_f32_16x16x32_bf16( \
                        afr[i], bgr[j], acc_g[i][j], 0, 0, 0);             \
                    acc_u[i][j] = __builtin_amdgcn_mfma_f32_16x16x32_bf16( \
                        afr[i], bur[j], acc_u[i][j], 0, 0, 0);             \
                }                                                          \
        }                                                                  \
    } while (0)

    const int nt = K / BK;                // 32 (even, >= 4)

    // Prologue: fill both buffers (16 outstanding); wait buf0 (->8).
    STAGE_F(As0, Bgs0, Bus0, 0);
    STAGE_F(As1, Bgs1, Bus1, 1);
    WAIT_VM8();
    raw_barrier();

    for (int t = 0; t + 2 < nt; t += 2) {
        COMPUTE_F(As0, Bgs0, Bus0);       // tile t (landed: prior wait)
        raw_barrier();                    // all waves done reading buf0
        STAGE_F(As0, Bgs0, Bus0, t + 2);  // 8 -> 16
        WAIT_VM8();                       // buf1 (tile t+1) landed
        raw_barrier();
        COMPUTE_F(As1, Bgs1, Bus1);       // tile t+1
        raw_barrier();
        STAGE_F(As1, Bgs1, Bus1, t + 3);  // 8 -> 16
        WAIT_VM8();                       // buf0 (tile t+2) landed
        raw_barrier();
    }
    // Epilogue: buf0 = tile nt-2 (landed), buf1 = tile nt-1 (8 in flight).
    COMPUTE_F(As0, Bgs0, Bus0);
    WAIT_VM0();
    raw_barrier();
    COMPUTE_F(As1, Bgs1, Bus1);
#undef STAGE_F
#undef COMPUTE_F

    // In-register epilogue: silu(gate)*up -> bf16 store. No LDS, no barrier.
#pragma unroll
    for (int i = 0; i < 4; ++i)
#pragma unroll
        for (int j = 0; j < 4; ++j)
#pragma unroll
            for (int r = 0; r < 4; ++r) {
                long long row = brow + wm + i * 16 + qk * 4 + r;
                long long col = bcol + wn + j * 16 + (lane & 15);
                float g = acc_g[i][j][r];
                float u = acc_u[i][j][r];
                float s = g / (1.0f + expf(-g));
                C[row * (long long)N + col] = __float2bfloat16(s * u);
            }
}

// ---------------------------------------------------------------------------
// down GEMM, R14 (kept, best-known): 256x256 tile, counted-vmcnt dbuf,
// 256 blocks 1/CU. Measured ~326us (vs 353/336/353 for prior structures).
// ---------------------------------------------------------------------------
__global__ __launch_bounds__(512, 2) void gemm_down8_kernel(
    const bf16* __restrict__ A,   // inter [M, K]
    const bf16* __restrict__ B,   // Wd    [N, K]
    float* __restrict__ C,        // out   [M, N]
    int M, int N, int K) {
    __shared__ __align__(16) bf16 smem[2 * 2 * 256 * BK];  // 128 KB dbuf
    bf16* As0 = smem;                      // 256x64 = 16384 elems (32 KB)
    bf16* Bs0 = smem + 16384;
    bf16* As1 = smem + 32768;
    bf16* Bs1 = smem + 49152;

    const int tid  = threadIdx.x;
    const int lane = tid & 63;
    const int wave = tid >> 6;            // 0..7
    const int wm   = (wave >> 2) * 128;   // 0,128
    const int wn   = (wave & 3) * 64;     // 0,64,128,192

    // XCD decode: b in [0,256) -> brow_blk = (b&7)*4 + (b>>6) in [0,32),
    // bcol_blk = (b>>3)&7. Bijective.
    const int b = blockIdx.x;
    const long long brow = (long long)((b & 7) * 4 + (b >> 6)) * 256;
    const long long bcol = (long long)((b >> 3) & 7) * 256;

    const int srow = tid >> 3;                       // 0..63
    const int skb  = ((tid & 7) ^ (srow & 7)) * 8;   // swizzled global col (elems)
    const bf16* gaR = A + (brow + srow) * (long long)K + skb;
    const bf16* gbR = B + (bcol + srow) * (long long)K + skb;
    const long long rstep = 64LL * K;                // 64-row group stride

    const int fm = wm + (lane & 15);
    const int fn = wn + (lane & 15);
    const int qk = lane >> 4;              // 0..3 (k-quad)

    f32x4 acc[8][4] = {};

#define STAGE_DOWN(dA, dB, t)                                              \
    do {                                                                   \
        long long off = (long long)(t) * BK;                               \
        _Pragma("unroll")                                                  \
        for (int r = 0; r < 4; ++r) {                                      \
            async_load16(gaR + r * rstep + off, (dA) + r * 4096 + tid * 8);\
            async_load16(gbR + r * rstep + off, (dB) + r * 4096 + tid * 8);\
        }                                                                  \
    } while (0)

#define COMPUTE_DOWN(sA, sB)                                               \
    do {                                                                   \
        _Pragma("unroll")                                                  \
        for (int h = 0; h < 2; ++h) {                                      \
            bf16x8 afr[8], bfr[4];                                         \
            const int hc = (h << 2) | qk;                                  \
            const int ccA = (hc ^ (fm & 7)) * 8;                           \
            const int ccB = (hc ^ (fn & 7)) * 8;                           \
            _Pragma("unroll")                                              \
            for (int i = 0; i < 8; ++i)                                    \
                afr[i] = *reinterpret_cast<const bf16x8*>(                 \
                    &(sA)[(fm + i * 16) * BK + ccA]);                      \
            _Pragma("unroll")                                              \
            for (int j = 0; j < 4; ++j)                                    \
                bfr[j] = *reinterpret_cast<const bf16x8*>(                 \
                    &(sB)[(fn + j * 16) * BK + ccB]);                      \
            _Pragma("unroll")                                              \
            for (int i = 0; i < 8; ++i)                                    \
                _Pragma("unroll")                                          \
                for (int j = 0; j < 4; ++j)                                \
                    acc[i][j] = __builtin_amdgcn_mfma_f32_16x16x32_bf16(   \
                        afr[i], bfr[j], acc[i][j], 0, 0, 0);               \
        }                                                                  \
    } while (0)

    const int nt = K / BK;                // 128 (even, >= 4)

    STAGE_DOWN(As0, Bs0, 0);
    STAGE_DOWN(As1, Bs1, 1);
    WAIT_VM8();
    raw_barrier();

    for (int t = 0; t + 2 < nt; t += 2) {
        COMPUTE_DOWN(As0, Bs0);           // tile t (landed: prior wait)
        raw_barrier();                    // all waves done reading buf0
        STAGE_DOWN(As0, Bs0, t + 2);      // 8 -> 16
        WAIT_VM8();                       // buf1 (tile t+1) landed
        raw_barrier();
        COMPUTE_DOWN(As1, Bs1);           // tile t+1
        raw_barrier();
        STAGE_DOWN(As1, Bs1, t + 3);      // 8 -> 16
        WAIT_VM8();                       // buf0 (tile t+2) landed
        raw_barrier();
    }
    COMPUTE_DOWN(As0, Bs0);
    WAIT_VM0();
    raw_barrier();
    COMPUTE_DOWN(As1, Bs1);
#undef STAGE_DOWN
#undef COMPUTE_DOWN

#pragma unroll
    for (int i = 0; i < 8; ++i)
#pragma unroll
        for (int j = 0; j < 4; ++j)
#pragma unroll
            for (int r = 0; r < 4; ++r) {
                long long row = brow + wm + i * 16 + qk * 4 + r;
                long long col = bcol + wn + j * 16 + (lane & 15);
                C[row * N + col] = acc[i][j][r];
            }
}

// ---------------------------------------------------------------------------
extern "C" void kernel_launch(void* const* d_in, const int* in_sizes, int n_in,
                              void* d_out, int out_size, void* d_ws, size_t ws_size,
                              hipStream_t stream) {
    const float* hs  = (const float*)d_in[0];   // [4,2048,2048] fp32
    const float* gcp = (const float*)d_in[1];
    const float* ucp = (const float*)d_in[2];
    const float* dcp = (const float*)d_in[3];

    const int M = 8192;        // 4*2048 tokens
    const int H = 2048;
    const int I = 8192;
    const int NW = H * I;
    const int n_ctrl_g = in_sizes[1];
    const int n_ctrl_u = in_sizes[2];
    const int n_ctrl_d = in_sizes[3];

    // workspace layout (all bf16): Xb | Wg | Wu | Wd | inter
    bf16* Xb    = (bf16*)d_ws;
    bf16* Wg    = Xb + (size_t)M * H;
    bf16* Wu    = Wg + (size_t)NW;
    bf16* Wd    = Wu + (size_t)NW;
    bf16* inter = Wd + (size_t)NW;

    const int nX8 = (M * H) / 8;
    cvt_f32_bf16_8_kernel<<<(nX8 + 255) / 256, 256, 0, stream>>>(
        (const float4*)hs, Xb, nX8);

    double step_g = (double)(n_ctrl_g - 1) / (double)(NW - 1);
    double step_u = (double)(n_ctrl_u - 1) / (double)(NW - 1);
    double step_d = (double)(n_ctrl_d - 1) / (double)(NW - 1);
    const int n8 = NW / 8;
    spline_recon8_kernel<<<(n8 + 255) / 256, 256, 0, stream>>>(gcp, Wg, n8, n_ctrl_g, step_g);
    spline_recon8_kernel<<<(n8 + 255) / 256, 256, 0, stream>>>(ucp, Wu, n8, n_ctrl_u, step_u);
    spline_recon8_kernel<<<(n8 + 255) / 256, 256, 0, stream>>>(dcp, Wd, n8, n_ctrl_d, step_d);

    // fused gate+up: inter = silu(X.Wg^T) * (X.Wu^T)   [M, I]
    // 256(M)x128(N) tiles, both-per-wave, counted-vmcnt dbuf.
    fused_gate_up2_kernel<<<dim3(I / 128, M / 256), 512, 0, stream>>>(
        Xb, Wg, Wu, inter, M, I, H);

    // down: out = inter . Wd^T  (fp32)   [M, H], 256x256 tiles, dbuf
    // counted-vmcnt pipeline, 256 blocks (1/CU) with XCD-aware decode.
    gemm_down8_kernel<<<256, 512, 0, stream>>>(
        inter, Wd, (float*)d_out, M, H, I);
}

// Round 15
// 817.221 us; speedup vs baseline: 1.3336x; 1.3336x over previous
//
#include <hip/hip_runtime.h>
#include <hip/hip_bf16.h>
#include <math.h>

using bf16 = __hip_bfloat16;
typedef __bf16 bf16x8 __attribute__((ext_vector_type(8)));
typedef float  f32x4  __attribute__((ext_vector_type(4)));

#define BK 64   // K-tile; row stride 128B, XOR-swizzled chunks

// ---------------------------------------------------------------------------
// Catmull-Rom spline reconstruction for ALL THREE weights in one launch:
// blockIdx.y selects (cp, w, n_ctrl, step). Per-element math identical to
// the single-weight kernel -> bit-identical outputs; saves 2 launch overheads.
// ---------------------------------------------------------------------------
__global__ void spline_recon8x3_kernel(const float* __restrict__ cp0,
                                       const float* __restrict__ cp1,
                                       const float* __restrict__ cp2,
                                       bf16* __restrict__ w0,
                                       bf16* __restrict__ w1,
                                       bf16* __restrict__ w2,
                                       int n8, int nc0, int nc1, int nc2,
                                       double s0, double s1, double s2) {
    int k8 = blockIdx.x * blockDim.x + threadIdx.x;
    if (k8 >= n8) return;
    const float* cp; bf16* w; int n_ctrl; double step;
    if (blockIdx.y == 0)      { cp = cp0; w = w0; n_ctrl = nc0; step = s0; }
    else if (blockIdx.y == 1) { cp = cp1; w = w1; n_ctrl = nc1; step = s1; }
    else                      { cp = cp2; w = w2; n_ctrl = nc2; step = s2; }
    long long kbase = (long long)k8 * 8;
    bf16x8 o;
#pragma unroll
    for (int u = 0; u < 8; ++u) {
        double t = (double)(kbase + u) * step;
        int i = (int)t;
        if (i > n_ctrl - 2) i = n_ctrl - 2;
        float f = (float)(t - (double)i);
        float p0 = cp[i > 0 ? i - 1 : 0];
        float p1 = cp[i];
        float p2 = cp[i + 1];
        float p3 = cp[(i + 2) <= (n_ctrl - 1) ? (i + 2) : (n_ctrl - 1)];
        float f2 = f * f;
        float f3 = f2 * f;
        float v = 0.5f * (2.0f * p1
                          + (p2 - p0) * f
                          + (2.0f * p0 - 5.0f * p1 + 4.0f * p2 - p3) * f2
                          + (3.0f * p1 - p0 - 3.0f * p2 + p3) * f3);
        o[u] = (__bf16)v;
    }
    *reinterpret_cast<bf16x8*>(w + kbase) = o;
}

// fp32 -> bf16 cast, 8 elements/thread
__global__ void cvt_f32_bf16_8_kernel(const float4* __restrict__ x,
                                      bf16* __restrict__ y, int n8) {
    int k = blockIdx.x * blockDim.x + threadIdx.x;
    if (k >= n8) return;
    float4 a = x[2 * k];
    float4 b = x[2 * k + 1];
    bf16x8 o;
    o[0] = (__bf16)a.x; o[1] = (__bf16)a.y; o[2] = (__bf16)a.z; o[3] = (__bf16)a.w;
    o[4] = (__bf16)b.x; o[5] = (__bf16)b.y; o[6] = (__bf16)b.z; o[7] = (__bf16)b.w;
    *reinterpret_cast<bf16x8*>(y + (long long)k * 8) = o;
}

__device__ __forceinline__ void async_load16(const bf16* g, bf16* l) {
    __builtin_amdgcn_global_load_lds(
        (const __attribute__((address_space(1))) void*)g,
        (__attribute__((address_space(3))) void*)l,
        16, 0, 0);
}

// raw barrier with compiler memory fences (prevents LDS op reordering across it)
__device__ __forceinline__ void raw_barrier() {
    asm volatile("" ::: "memory");
    __builtin_amdgcn_s_barrier();
    asm volatile("" ::: "memory");
}

#define WAIT_VM8()  asm volatile("s_waitcnt vmcnt(8)" ::: "memory")
#define WAIT_VM0()  asm volatile("s_waitcnt vmcnt(0)" ::: "memory")

// ---------------------------------------------------------------------------
// Fused gate+up GEMM — R5 drain0 version, PERMANENT (measured 479-500us /
// ~55% MfmaUtil across six nodes; deterministic absmax 0.03125).
// Three pipeline attempts failed: R12 (dbuf 96KB, 1blk/CU): 593us, FETCH
// +200MB; R15 (256x128 both-per-wave): 815us; R16 (BK=32 dbuf in 48KB):
// RACY (raw s_barrier lacks lgkmcnt drain -> WAR on rebind; rule-#18 class)
// and ~558us anyway. Conclusion: for K=2048 with L2-hot W panels, fused's
// optimum is 2-block TLP + resident L2 window + __syncthreads (whose full
// drain is also what makes it race-free). Do not touch again.
// ---------------------------------------------------------------------------
__global__ __launch_bounds__(512, 4) void fused_gate_up_kernel(
    const bf16* __restrict__ A,    // X  [M, K]
    const bf16* __restrict__ Bg,   // Wg [N, K]
    const bf16* __restrict__ Bu,   // Wu [N, K]
    bf16* __restrict__ C,          // inter [M, N]
    int M, int N, int K) {
    __shared__ __align__(16) bf16 smem[3 * 128 * BK];   // 48 KB
    bf16* As  = smem;
    bf16* Bgs = smem + 128 * BK;
    bf16* Bus = smem + 2 * 128 * BK;

    const int tid  = threadIdx.x;
    const int lane = tid & 63;
    const int wave = tid >> 6;
    const int wq   = wave & 3;
    const int wm   = (wq >> 1) * 64;
    const int wn   = (wq & 1) * 64;
    const bool is_gate = wave < 4;

    const long long brow = (long long)blockIdx.y * 128;
    const long long bcol = (long long)blockIdx.x * 128;

    const int srow = tid >> 3;                       // 0..63
    const int skb  = ((tid & 7) ^ (srow & 7)) * 8;   // swizzled global col (elems)
    const bf16* ga0 = A  + (brow + srow) * (long long)K + skb;
    const bf16* ga1 = A  + (brow + srow + 64) * (long long)K + skb;
    const bf16* gg0 = Bg + (bcol + srow) * (long long)K + skb;
    const bf16* gg1 = Bg + (bcol + srow + 64) * (long long)K + skb;
    const bf16* gu0 = Bu + (bcol + srow) * (long long)K + skb;
    const bf16* gu1 = Bu + (bcol + srow + 64) * (long long)K + skb;
    bf16* la0 = As  + tid * 8;
    bf16* la1 = As  + 4096 + tid * 8;
    bf16* lg0 = Bgs + tid * 8;
    bf16* lg1 = Bgs + 4096 + tid * 8;
    bf16* lu0 = Bus + tid * 8;
    bf16* lu1 = Bus + 4096 + tid * 8;

    const bf16* Bsel = is_gate ? Bgs : Bus;
    const int fm = wm + (lane & 15);
    const int fn = wn + (lane & 15);
    const int qk = lane >> 4;              // 0..3 (k-quad)

    f32x4 acc[4][4] = {};

    for (int k0 = 0; k0 < K; k0 += BK) {
        async_load16(ga0, la0); ga0 += BK;
        async_load16(ga1, la1); ga1 += BK;
        async_load16(gg0, lg0); gg0 += BK;
        async_load16(gg1, lg1); gg1 += BK;
        async_load16(gu0, lu0); gu0 += BK;
        async_load16(gu1, lu1); gu1 += BK;
        __syncthreads();   // drains vmcnt for global_load_lds

#pragma unroll
        for (int h = 0; h < 2; ++h) {
            bf16x8 afr[4], bfr[4];
            const int hc = (h << 2) | qk;          // wanted colchunk 0..7
            const int ccA = (hc ^ (fm & 7)) * 8;   // fm&7 invariant over i (+16)
            const int ccB = (hc ^ (fn & 7)) * 8;
#pragma unroll
            for (int i = 0; i < 4; ++i)
                afr[i] = *reinterpret_cast<const bf16x8*>(
                    &As[(fm + i * 16) * BK + ccA]);
#pragma unroll
            for (int j = 0; j < 4; ++j)
                bfr[j] = *reinterpret_cast<const bf16x8*>(
                    &Bsel[(fn + j * 16) * BK + ccB]);
#pragma unroll
            for (int i = 0; i < 4; ++i)
#pragma unroll
                for (int j = 0; j < 4; ++j)
                    acc[i][j] = __builtin_amdgcn_mfma_f32_16x16x32_bf16(
                        afr[i], bfr[j], acc[i][j], 0, 0, 0);
        }
        __syncthreads();
    }

    // Epilogue: combine silu(gate)*up through LDS (reuses smem as Epi[128][128])
    bf16* Epi = smem;
    if (is_gate) {
#pragma unroll
        for (int i = 0; i < 4; ++i)
#pragma unroll
            for (int j = 0; j < 4; ++j)
#pragma unroll
                for (int r = 0; r < 4; ++r) {
                    int row = wm + i * 16 + (lane >> 4) * 4 + r;
                    int col = wn + j * 16 + (lane & 15);
                    float v = acc[i][j][r];
                    float s = v / (1.0f + expf(-v));
                    Epi[row * 128 + col] = __float2bfloat16(s);
                }
    }
    __syncthreads();
    if (!is_gate) {
#pragma unroll
        for (int i = 0; i < 4; ++i)
#pragma unroll
            for (int j = 0; j < 4; ++j)
#pragma unroll
                for (int r = 0; r < 4; ++r) {
                    int row = wm + i * 16 + (lane >> 4) * 4 + r;
                    int col = wn + j * 16 + (lane & 15);
                    float s = __bfloat162float(Epi[row * 128 + col]);
                    float v = s * acc[i][j][r];
                    C[(brow + row) * (long long)N + bcol + col] = __float2bfloat16(v);
                }
    }
}

// ---------------------------------------------------------------------------
// down GEMM, R14 (kept, best-known): 256x256 tile, counted-vmcnt dbuf,
// 256 blocks 1/CU. Measured ~326us; deterministic across 6 nodes.
// ---------------------------------------------------------------------------
__global__ __launch_bounds__(512, 2) void gemm_down8_kernel(
    const bf16* __restrict__ A,   // inter [M, K]
    const bf16* __restrict__ B,   // Wd    [N, K]
    float* __restrict__ C,        // out   [M, N]
    int M, int N, int K) {
    __shared__ __align__(16) bf16 smem[2 * 2 * 256 * BK];  // 128 KB dbuf
    bf16* As0 = smem;                      // 256x64 = 16384 elems (32 KB)
    bf16* Bs0 = smem + 16384;
    bf16* As1 = smem + 32768;
    bf16* Bs1 = smem + 49152;

    const int tid  = threadIdx.x;
    const int lane = tid & 63;
    const int wave = tid >> 6;            // 0..7
    const int wm   = (wave >> 2) * 128;   // 0,128
    const int wn   = (wave & 3) * 64;     // 0,64,128,192

    // XCD decode: b in [0,256) -> brow_blk = (b&7)*4 + (b>>6) in [0,32),
    // bcol_blk = (b>>3)&7. Bijective.
    const int b = blockIdx.x;
    const long long brow = (long long)((b & 7) * 4 + (b >> 6)) * 256;
    const long long bcol = (long long)((b >> 3) & 7) * 256;

    const int srow = tid >> 3;                       // 0..63
    const int skb  = ((tid & 7) ^ (srow & 7)) * 8;   // swizzled global col (elems)
    const bf16* gaR = A + (brow + srow) * (long long)K + skb;
    const bf16* gbR = B + (bcol + srow) * (long long)K + skb;
    const long long rstep = 64LL * K;                // 64-row group stride

    const int fm = wm + (lane & 15);
    const int fn = wn + (lane & 15);
    const int qk = lane >> 4;              // 0..3 (k-quad)

    f32x4 acc[8][4] = {};

#define STAGE_DOWN(dA, dB, t)                                              \
    do {                                                                   \
        long long off = (long long)(t) * BK;                               \
        _Pragma("unroll")                                                  \
        for (int r = 0; r < 4; ++r) {                                      \
            async_load16(gaR + r * rstep + off, (dA) + r * 4096 + tid * 8);\
            async_load16(gbR + r * rstep + off, (dB) + r * 4096 + tid * 8);\
        }                                                                  \
    } while (0)

#define COMPUTE_DOWN(sA, sB)                                               \
    do {                                                                   \
        _Pragma("unroll")                                                  \
        for (int h = 0; h < 2; ++h) {                                      \
            bf16x8 afr[8], bfr[4];                                         \
            const int hc = (h << 2) | qk;                                  \
            const int ccA = (hc ^ (fm & 7)) * 8;                           \
            const int ccB = (hc ^ (fn & 7)) * 8;                           \
            _Pragma("unroll")                                              \
            for (int i = 0; i < 8; ++i)                                    \
                afr[i] = *reinterpret_cast<const bf16x8*>(                 \
                    &(sA)[(fm + i * 16) * BK + ccA]);                      \
            _Pragma("unroll")                                              \
            for (int j = 0; j < 4; ++j)                                    \
                bfr[j] = *reinterpret_cast<const bf16x8*>(                 \
                    &(sB)[(fn + j * 16) * BK + ccB]);                      \
            _Pragma("unroll")                                              \
            for (int i = 0; i < 8; ++i)                                    \
                _Pragma("unroll")                                          \
                for (int j = 0; j < 4; ++j)                                \
                    acc[i][j] = __builtin_amdgcn_mfma_f32_16x16x32_bf16(   \
                        afr[i], bfr[j], acc[i][j], 0, 0, 0);               \
        }                                                                  \
    } while (0)

    const int nt = K / BK;                // 128 (even, >= 4)

    STAGE_DOWN(As0, Bs0, 0);
    STAGE_DOWN(As1, Bs1, 1);
    WAIT_VM8();
    raw_barrier();

    for (int t = 0; t + 2 < nt; t += 2) {
        COMPUTE_DOWN(As0, Bs0);           // tile t (landed: prior wait)
        raw_barrier();                    // all waves done reading buf0
        STAGE_DOWN(As0, Bs0, t + 2);      // 8 -> 16
        WAIT_VM8();                       // buf1 (tile t+1) landed
        raw_barrier();
        COMPUTE_DOWN(As1, Bs1);           // tile t+1
        raw_barrier();
        STAGE_DOWN(As1, Bs1, t + 3);      // 8 -> 16
        WAIT_VM8();                       // buf0 (tile t+2) landed
        raw_barrier();
    }
    COMPUTE_DOWN(As0, Bs0);
    WAIT_VM0();
    raw_barrier();
    COMPUTE_DOWN(As1, Bs1);
#undef STAGE_DOWN
#undef COMPUTE_DOWN

#pragma unroll
    for (int i = 0; i < 8; ++i)
#pragma unroll
        for (int j = 0; j < 4; ++j)
#pragma unroll
            for (int r = 0; r < 4; ++r) {
                long long row = brow + wm + i * 16 + qk * 4 + r;
                long long col = bcol + wn + j * 16 + (lane & 15);
                C[row * N + col] = acc[i][j][r];
            }
}

// ---------------------------------------------------------------------------
extern "C" void kernel_launch(void* const* d_in, const int* in_sizes, int n_in,
                              void* d_out, int out_size, void* d_ws, size_t ws_size,
                              hipStream_t stream) {
    const float* hs  = (const float*)d_in[0];   // [4,2048,2048] fp32
    const float* gcp = (const float*)d_in[1];
    const float* ucp = (const float*)d_in[2];
    const float* dcp = (const float*)d_in[3];

    const int M = 8192;        // 4*2048 tokens
    const int H = 2048;
    const int I = 8192;
    const int NW = H * I;
    const int n_ctrl_g = in_sizes[1];
    const int n_ctrl_u = in_sizes[2];
    const int n_ctrl_d = in_sizes[3];

    // workspace layout (all bf16): Xb | Wg | Wu | Wd | inter
    bf16* Xb    = (bf16*)d_ws;
    bf16* Wg    = Xb + (size_t)M * H;
    bf16* Wu    = Wg + (size_t)NW;
    bf16* Wd    = Wu + (size_t)NW;
    bf16* inter = Wd + (size_t)NW;

    const int nX8 = (M * H) / 8;
    cvt_f32_bf16_8_kernel<<<(nX8 + 255) / 256, 256, 0, stream>>>(
        (const float4*)hs, Xb, nX8);

    double step_g = (double)(n_ctrl_g - 1) / (double)(NW - 1);
    double step_u = (double)(n_ctrl_u - 1) / (double)(NW - 1);
    double step_d = (double)(n_ctrl_d - 1) / (double)(NW - 1);
    const int n8 = NW / 8;
    spline_recon8x3_kernel<<<dim3((n8 + 255) / 256, 3), 256, 0, stream>>>(
        gcp, ucp, dcp, Wg, Wu, Wd, n8,
        n_ctrl_g, n_ctrl_u, n_ctrl_d, step_g, step_u, step_d);

    // fused gate+up: inter = silu(X.Wg^T) * (X.Wu^T)   [M, I]
    fused_gate_up_kernel<<<dim3(I / 128, M / 128), 512, 0, stream>>>(
        Xb, Wg, Wu, inter, M, I, H);

    // down: out = inter . Wd^T  (fp32)   [M, H], 256x256 tiles, dbuf
    // counted-vmcnt pipeline, 256 blocks (1/CU) with XCD-aware decode.
    gemm_down8_kernel<<<256, 512, 0, stream>>>(
        inter, Wd, (float*)d_out, M, H, I);
}